// Round 9
// baseline (367.023 us; speedup 1.0000x reference)
//
#include <hip/hip_runtime.h>

// GraphAttention: B=4, N=2048, F=256, H=8, F_=64; out [B, N, 512].
// 4 dispatches:
//  k_prep   : A->bitmask; X,W->bf16; zero acc/l partial buffers; init maxn.
//  k_gemm1  : h=X@W (MFMA, h_t transposed) + fused epilogue computing
//             att_s, E=exp(att_n), E5=exp(0.2*att_n), per-bh max(att_n).
//  k_attn_av: j-split (S=4) fused masked softmax @ h. P built from tables:
//             p = (E>exp(-s) ? exp(s-c)*E : exp(0.2s-c)*E5) * maskbit, with
//             c = leaky(s+maxn) >= row max (softmax shift-invariant).
//             Partial acc (fp32) and row-sums l (ones-MFMA) atomicAdd'ed.
//  k_combine: out = relu(acc / l), cast to input dtype.
// Input dtype detected from A[0][0] (self-loop: fp32 word == 1.0f).

constexpr int GN  = 2048;
constexpr int GHF = 512;

using sh8    = __attribute__((ext_vector_type(8))) short;          // 8 bf16
using us4g   = __attribute__((ext_vector_type(4))) unsigned short;
using f32x4g = __attribute__((ext_vector_type(4))) float;
using i32x4g = __attribute__((ext_vector_type(4))) int;

__device__ inline float gat_bf2f(unsigned short u) {
    union { unsigned int i; float f; } c; c.i = ((unsigned int)u) << 16; return c.f;
}
__device__ inline unsigned short gat_f2bf(float f) {
    union { float f; unsigned int i; } c; c.f = f;
    return (unsigned short)((c.i + 0x7fffu + ((c.i >> 16) & 1u)) >> 16); // RNE
}
__device__ inline int gat_isf32(const float* __restrict__ Aw) {
    float a = Aw[0];
    return (a == 0.0f) || (a == 1.0f);
}
__device__ inline unsigned int gat_enc(float f) {
    union { float f; unsigned int u; } c; c.f = f;
    return (c.u & 0x80000000u) ? ~c.u : (c.u | 0x80000000u);
}
__device__ inline float gat_dec(unsigned int e) {
    union { float f; unsigned int u; } c;
    c.u = (e & 0x80000000u) ? (e & 0x7fffffffu) : ~e;
    return c.f;
}

__global__ void GraphAttention_62981400429165_kernel() {}

// ---------------- workspace layout (bytes) ----------------
constexpr size_t OFF_HT   = 256;                       // h_t bf16       8 MB
constexpr size_t OFF_ATTS = OFF_HT   + 8388608;        // att_s f32    256 KB
constexpr size_t OFF_E    = OFF_ATTS + 262144;         // exp(n)       256 KB
constexpr size_t OFF_E5   = OFF_E    + 262144;         // exp(.2n)     256 KB
constexpr size_t OFF_MASK = OFF_E5   + 262144;         // bitmask        2 MB
constexpr size_t OFF_MAXN = OFF_MASK + 2097152;        // 32 u32
constexpr size_t OFF_XC   = OFF_MAXN + 256;            // X bf16         4 MB
constexpr size_t OFF_WC   = OFF_XC   + 4194304;        // W bf16       256 KB
constexpr size_t OFF_ACC  = OFF_WC   + 262144;         // acc f32       16 MB
constexpr size_t OFF_PL   = OFF_ACC  + 16777216;       // l f32        256 KB
// total ~31.3 MB

// --------------------------------------------------------------------------
// k_prep: grid 65536 x 256. All blocks: A->mask. Blocks 0..8191: X->bf16.
// 8192..8703: W->bf16. 16384..33023: zero acc+l (17039360 B = 4259840 dw).
// Block 0: init maxn.
// --------------------------------------------------------------------------
__global__ __launch_bounds__(256) void k_prep(const void* __restrict__ Araw,
                                              const void* __restrict__ Xraw,
                                              const void* __restrict__ Wraw,
                                              unsigned long long* __restrict__ mask,
                                              unsigned int* __restrict__ maxn_enc,
                                              unsigned short* __restrict__ Xc,
                                              unsigned short* __restrict__ Wc,
                                              float* __restrict__ zbase) {
    int tid = threadIdx.x, blk = blockIdx.x;
    int isf = gat_isf32((const float*)Araw);
    if (blk == 0 && tid < 32) maxn_enc[tid] = 0u;
    size_t idx = (size_t)blk * 256 + tid;
    int nz;
    if (isf) nz = (((const float*)Araw)[idx] != 0.0f);
    else     nz = (((const unsigned short*)Araw)[idx] != 0);
    unsigned long long bal = __ballot(nz);
    if ((tid & 63) == 0) mask[idx >> 6] = bal;
    if (blk < 8192) {
        int i = blk * 256 + tid;
        Xc[i] = isf ? gat_f2bf(((const float*)Xraw)[i]) : ((const unsigned short*)Xraw)[i];
    } else if (blk < 8704) {
        int i = (blk - 8192) * 256 + tid;
        Wc[i] = isf ? gat_f2bf(((const float*)Wraw)[i]) : ((const unsigned short*)Wraw)[i];
    } else if (blk >= 16384 && blk < 33024) {
        zbase[(size_t)(blk - 16384) * 256 + tid] = 0.0f;
    }
}

// --------------------------------------------------------------------------
// k_gemm1: h = X @ W per (b,h) + fused att epilogue.
// grid 256 (bh*8+it) x 256 (4 waves x 64 rows).
// --------------------------------------------------------------------------
constexpr int LDW = 264;
__global__ __launch_bounds__(256) void k_gemm1(const unsigned short* __restrict__ Xc,
                                               const unsigned short* __restrict__ Wc,
                                               const void* __restrict__ aSraw,
                                               const void* __restrict__ aNraw,
                                               const float* __restrict__ Aw,
                                               unsigned short* __restrict__ h_t,
                                               float* __restrict__ att_s,
                                               float* __restrict__ Eb,
                                               float* __restrict__ E5b,
                                               unsigned int* __restrict__ maxn_enc) {
    int blk = blockIdx.x;
    int bh = blk >> 3, it = blk & 7;
    int b = bh >> 3, hh = bh & 7;
    int isf = gat_isf32(Aw);
    __shared__ unsigned short Wt[64 * LDW];
    for (int idx = threadIdx.x; idx < 256 * 64; idx += 256) {
        int k = idx >> 6, col = idx & 63;
        Wt[col * LDW + k] = Wc[(hh * 256 + k) * 64 + col];
    }
    __syncthreads();
#if defined(__gfx950__)
    int wave = threadIdx.x >> 6, lane = threadIdx.x & 63;
    int lrw = lane & 15, quad = lane >> 4;
    int row0 = it * 256 + wave * 64;
    f32x4g acc[4][4] = {};
    for (int k0 = 0; k0 < 256; k0 += 32) {
        sh8 a[4], w[4];
        for (int rt = 0; rt < 4; rt++)
            a[rt] = *(const sh8*)&Xc[((size_t)(b * GN) + row0 + rt * 16 + lrw) * 256 + k0 + quad * 8];
        for (int ct = 0; ct < 4; ct++)
            w[ct] = *(const sh8*)&Wt[(ct * 16 + lrw) * LDW + k0 + quad * 8];
        for (int rt = 0; rt < 4; rt++)
            for (int ct = 0; ct < 4; ct++)
                acc[rt][ct] = __builtin_amdgcn_mfma_f32_16x16x32_bf16(a[rt], w[ct], acc[rt][ct], 0, 0, 0);
    }
    for (int rt = 0; rt < 4; rt++)
        for (int ct = 0; ct < 4; ct++) {
            int col = ct * 16 + lrw;
            int row = row0 + rt * 16 + quad * 4;
            us4g v;
            v[0] = gat_f2bf(acc[rt][ct][0]);
            v[1] = gat_f2bf(acc[rt][ct][1]);
            v[2] = gat_f2bf(acc[rt][ct][2]);
            v[3] = gat_f2bf(acc[rt][ct][3]);
            *(us4g*)&h_t[((size_t)(bh * 64 + col)) * GN + row] = v;
        }
    // ---- fused att epilogue: att_s, E, E5, maxn ----
    float as_l[4], an_l[4];
    for (int ct = 0; ct < 4; ct++) {
        int col = hh * 64 + ct * 16 + lrw;
        as_l[ct] = isf ? ((const float*)aSraw)[col] : gat_bf2f(((const unsigned short*)aSraw)[col]);
        an_l[ct] = isf ? ((const float*)aNraw)[col] : gat_bf2f(((const unsigned short*)aNraw)[col]);
    }
    float wmax = -3e38f;
    for (int rt = 0; rt < 4; rt++)
        for (int r = 0; r < 4; r++) {
            float ps = acc[rt][0][r] * as_l[0] + acc[rt][1][r] * as_l[1]
                     + acc[rt][2][r] * as_l[2] + acc[rt][3][r] * as_l[3];
            float pn = acc[rt][0][r] * an_l[0] + acc[rt][1][r] * an_l[1]
                     + acc[rt][2][r] * an_l[2] + acc[rt][3][r] * an_l[3];
            for (int off = 1; off < 16; off <<= 1) {
                ps += __shfl_xor(ps, off);
                pn += __shfl_xor(pn, off);
            }
            int row = row0 + rt * 16 + quad * 4 + r;
            if (lrw == 0) {
                att_s[bh * GN + row] = ps;
                Eb[bh * GN + row]  = __expf(pn);
                E5b[bh * GN + row] = __expf(0.2f * pn);
            }
            wmax = fmaxf(wmax, pn);
        }
    wmax = fmaxf(wmax, __shfl_xor(wmax, 16));
    wmax = fmaxf(wmax, __shfl_xor(wmax, 32));
    if (lane == 0) atomicMax(&maxn_enc[bh], gat_enc(wmax));
#else
    // fallback: thread per row
    int row = it * 256 + threadIdx.x;
    float hrow[64];
    for (int col = 0; col < 64; col++) {
        float s = 0.f;
        for (int k = 0; k < 256; k++)
            s += gat_bf2f(Xc[((size_t)(b * GN) + row) * 256 + k]) * gat_bf2f(Wt[col * LDW + k]);
        hrow[col] = s;
        h_t[((size_t)(bh * 64 + col)) * GN + row] = gat_f2bf(s);
    }
    float ps = 0.f, pn = 0.f;
    for (int col = 0; col < 64; col++) {
        float as = isf ? ((const float*)aSraw)[hh * 64 + col] : gat_bf2f(((const unsigned short*)aSraw)[hh * 64 + col]);
        float an = isf ? ((const float*)aNraw)[hh * 64 + col] : gat_bf2f(((const unsigned short*)aNraw)[hh * 64 + col]);
        ps += hrow[col] * as;
        pn += hrow[col] * an;
    }
    att_s[bh * GN + row] = ps;
    Eb[bh * GN + row]  = __expf(pn);
    E5b[bh * GN + row] = __expf(0.2f * pn);
    atomicMax(&maxn_enc[bh], gat_enc(pn));
#endif
}

// --------------------------------------------------------------------------
// k_attn_av: j-split fused softmax @ h. grid 4096 (bh=blk&31, it=(blk>>5)&31,
// js=blk>>10), 128 thr = 2 waves x 32 rows. Each block: j in [js*512, +512).
// Table-based P (no exp in loop), partial acc/l via fp32 atomicAdd.
// --------------------------------------------------------------------------
__global__ __launch_bounds__(128, 6) void k_attn_av(const unsigned int* __restrict__ mask32,
                                                    const unsigned short* __restrict__ h_t,
                                                    const float* __restrict__ att_s,
                                                    const float* __restrict__ Eb,
                                                    const float* __restrict__ E5b,
                                                    const unsigned int* __restrict__ maxn_enc,
                                                    float* __restrict__ accb,
                                                    float* __restrict__ plb) {
    int blk = blockIdx.x;
    int bh = blk & 31, it = (blk >> 5) & 31, js = blk >> 10;
    int b = bh >> 3;
    int i0 = it * 64, j0 = js * 512;
    int tid = threadIdx.x;
    float maxn = gat_dec(maxn_enc[bh]);
    const float* Ep  = Eb  + (size_t)bh * GN + j0;
    const float* E5p = E5b + (size_t)bh * GN + j0;
    const unsigned short* hb = h_t + (size_t)bh * 64 * GN;
#if defined(__gfx950__)
    int wave = tid >> 6, lane = tid & 63, lrw = lane & 15, quad = lane >> 4;
    int kq = quad * 8;
    int row0 = i0 + wave * 32 + lrw;
    int row1 = row0 + 16;
    float s0 = att_s[bh * GN + row0];
    float s1 = att_s[bh * GN + row1];
    float z0 = s0 + maxn, z1 = s1 + maxn;
    float c0 = fmaxf(z0, 0.2f * z0), c1 = fmaxf(z1, 0.2f * z1);
    float k10 = __expf(s0 - c0), k20 = __expf(0.2f * s0 - c0), T00 = __expf(-s0);
    float k11 = __expf(s1 - c1), k21 = __expf(0.2f * s1 - c1), T01 = __expf(-s1);
    const unsigned int* mr0 = mask32 + ((size_t)(b * GN) + row0) * 64 + js * 16;
    const unsigned int* mr1 = mask32 + ((size_t)(b * GN) + row1) * 64 + js * 16;
    f32x4g acc0[4] = {}, acc1[4] = {};
    f32x4g accl0 = {}, accl1 = {};
    sh8 ones;
#pragma unroll
    for (int e = 0; e < 8; e++) ones[e] = (short)0x3f80;

    for (int jc = 0; jc < 16; jc++) {
        int jq = jc * 32 + kq;
        f32x4g eA  = *(const f32x4g*)&Ep[jq];
        f32x4g eB  = *(const f32x4g*)&Ep[jq + 4];
        f32x4g e5A = *(const f32x4g*)&E5p[jq];
        f32x4g e5B = *(const f32x4g*)&E5p[jq + 4];
        unsigned int w0 = mr0[jc] >> kq;
        unsigned int w1 = mr1[jc] >> kq;
        unsigned int q0[8], q1[8];
#pragma unroll
        for (int e = 0; e < 8; e++) {
            float Ev  = (e < 4) ? eA[e]  : eB[e - 4];
            float E5v = (e < 4) ? e5A[e] : e5B[e - 4];
            float p0 = (Ev > T00) ? (k10 * Ev) : (k20 * E5v);
            float p1 = (Ev > T01) ? (k11 * Ev) : (k21 * E5v);
            p0 = ((w0 >> e) & 1u) ? p0 : 0.0f;
            p1 = ((w1 >> e) & 1u) ? p1 : 0.0f;
            q0[e] = __float_as_uint(p0);
            q1[e] = __float_as_uint(p1);
        }
        i32x4g f0, f1;
#pragma unroll
        for (int pp = 0; pp < 4; pp++) {   // truncation pack (bias cancels in l)
            f0[pp] = (int)((q0[2 * pp] >> 16) | (q0[2 * pp + 1] & 0xffff0000u));
            f1[pp] = (int)((q1[2 * pp] >> 16) | (q1[2 * pp + 1] & 0xffff0000u));
        }
        sh8 af0 = *(sh8*)&f0;
        sh8 af1 = *(sh8*)&f1;
#pragma unroll
        for (int ct = 0; ct < 4; ct++) {
            sh8 bf = *(const sh8*)&hb[((size_t)(ct * 16 + lrw)) * GN + j0 + jq];
            acc0[ct] = __builtin_amdgcn_mfma_f32_16x16x32_bf16(af0, bf, acc0[ct], 0, 0, 0);
            acc1[ct] = __builtin_amdgcn_mfma_f32_16x16x32_bf16(af1, bf, acc1[ct], 0, 0, 0);
        }
        accl0 = __builtin_amdgcn_mfma_f32_16x16x32_bf16(af0, ones, accl0, 0, 0, 0);
        accl1 = __builtin_amdgcn_mfma_f32_16x16x32_bf16(af1, ones, accl1, 0, 0, 0);
    }
    // ---- accumulate partials ----
    size_t tbase = ((size_t)(bh * 32 + it)) * 64;
    float* pa = accb + tbase * 64;
#pragma unroll
    for (int r = 0; r < 4; r++) {
        int rl0 = wave * 32 + quad * 4 + r;
        int rl1 = rl0 + 16;
#pragma unroll
        for (int ct = 0; ct < 4; ct++) {
            int col = ct * 16 + lrw;
            atomicAdd(&pa[(size_t)rl0 * 64 + col], acc0[ct][r]);
            atomicAdd(&pa[(size_t)rl1 * 64 + col], acc1[ct][r]);
        }
        if (lrw == 0) {
            atomicAdd(&plb[tbase + rl0], accl0[r]);
            atomicAdd(&plb[tbase + rl1], accl1[r]);
        }
    }
#else
    // fallback: thread per (row, 32-col half) over local j-range
    int row = i0 + (tid >> 1), chh = (tid & 1) * 32;
    const unsigned int* mr = mask32 + ((size_t)(b * GN) + row) * 64 + js * 16;
    float s = att_s[bh * GN + row];
    float z = s + maxn;
    float c = fmaxf(z, 0.2f * z);
    float k1 = __expf(s - c), k2 = __expf(0.2f * s - c), T0 = __expf(-s);
    float l = 0.f;
    float accS[32] = {};
    for (int j = 0; j < 512; j++) {
        if (!((mr[j >> 5] >> (j & 31)) & 1u)) continue;
        float Ev = Ep[j], E5v = E5p[j];
        float p = (Ev > T0) ? (k1 * Ev) : (k2 * E5v);
        union { float f; unsigned int u; } t; t.f = p; t.u &= 0xffff0000u;
        l += t.f;
        for (int cc = 0; cc < 32; cc++)
            accS[cc] += t.f * gat_bf2f(hb[(size_t)(chh + cc) * GN + j0 + j]);
    }
    size_t tbase = ((size_t)(bh * 32 + it)) * 64 + (tid >> 1);
    for (int cc = 0; cc < 32; cc++)
        atomicAdd(&accb[tbase * 64 + chh + cc], accS[cc]);
    if ((tid & 1) == 0) atomicAdd(&plb[tbase], l);
#endif
}

// --------------------------------------------------------------------------
// k_combine: out = relu(acc / l). grid 4096 x 256 (1M threads x 4 cols).
// --------------------------------------------------------------------------
__global__ __launch_bounds__(256) void k_combine(const float* __restrict__ accb,
                                                 const float* __restrict__ plb,
                                                 const float* __restrict__ Aw,
                                                 void* __restrict__ outv) {
    int isf = gat_isf32(Aw);
    int gid = blockIdx.x * 256 + threadIdx.x;        // 0..1048575
    int col4 = gid & 15;
    int rloc = (gid >> 4) & 63;
    int itb  = gid >> 10;                            // bh*32+it
    size_t base = (((size_t)itb * 64 + rloc) * 64) + col4 * 4;
    f32x4g v = *(const f32x4g*)&accb[base];
    float li = 1.0f / plb[(size_t)itb * 64 + rloc];
    int bh = itb >> 5, it = itb & 31;
    int b = bh >> 3, hh = bh & 7;
    int rg = it * 64 + rloc;
    size_t o = ((size_t)(b * GN) + rg) * GHF + hh * 64 + col4 * 4;
    float r0 = fmaxf(v[0] * li, 0.f), r1 = fmaxf(v[1] * li, 0.f);
    float r2 = fmaxf(v[2] * li, 0.f), r3 = fmaxf(v[3] * li, 0.f);
    if (isf) {
        f32x4g ov = {r0, r1, r2, r3};
        *(f32x4g*)&((float*)outv)[o] = ov;
    } else {
        us4g ov;
        ov[0] = gat_f2bf(r0); ov[1] = gat_f2bf(r1);
        ov[2] = gat_f2bf(r2); ov[3] = gat_f2bf(r3);
        *(us4g*)&((unsigned short*)outv)[o] = ov;
    }
}

// --------------------------------------------------------------------------
extern "C" void kernel_launch(void* const* d_in, const int* in_sizes, int n_in,
                              void* d_out, int out_size, void* d_ws, size_t ws_size,
                              hipStream_t stream) {
    const void* X  = d_in[0];
    const void* A  = d_in[1];
    const void* W  = d_in[2];
    const void* aS = d_in[3];
    const void* aN = d_in[4];

    char* ws = (char*)d_ws;
    unsigned short* h_t = (unsigned short*)(ws + OFF_HT);
    float* att_s = (float*)(ws + OFF_ATTS);
    float* Eb    = (float*)(ws + OFF_E);
    float* E5b   = (float*)(ws + OFF_E5);
    unsigned long long* mask = (unsigned long long*)(ws + OFF_MASK);
    unsigned int* maxn_enc = (unsigned int*)(ws + OFF_MAXN);
    unsigned short* Xc = (unsigned short*)(ws + OFF_XC);
    unsigned short* Wc = (unsigned short*)(ws + OFF_WC);
    float* accb = (float*)(ws + OFF_ACC);
    float* plb  = (float*)(ws + OFF_PL);

    k_prep<<<65536, 256, 0, stream>>>(A, X, W, mask, maxn_enc, Xc, Wc, accb);
    k_gemm1<<<256, 256, 0, stream>>>(Xc, Wc, aS, aN, (const float*)A,
                                     h_t, att_s, Eb, E5b, maxn_enc);
    k_attn_av<<<4096, 128, 0, stream>>>((const unsigned int*)mask, h_t,
                                        att_s, Eb, E5b, maxn_enc, accb, plb);
    k_combine<<<4096, 256, 0, stream>>>(accb, plb, (const float*)A, d_out);
}

// Round 10
// 299.377 us; speedup vs baseline: 1.2260x; 1.2260x over previous
//
#include <hip/hip_runtime.h>

// GraphAttention: B=4, N=2048, F=256, H=8, F_=64; out [B, N, 512].
// 3 dispatches:
//  k_mask_conv: A->bitmask (+init maxn); X,W->bf16 (extra blocks).
//  k_gemm1    : h=X@W (MFMA, h_t transposed) + fused epilogue: att_s,
//               E=exp(att_n), E5=exp(0.2*att_n), per-bh max(att_n).
//  k_attn_av  : fused masked softmax @ h, table-based P (no exp in loop):
//               p = (E>exp(-s) ? exp(s-c)*E : exp(0.2s-c)*E5) * maskbit,
//               c = leaky(s+maxn) >= row max (softmax shift-invariant).
//               16 rows/wave -> 4096 waves (4/SIMD). l via ones-MFMA.
//               No LDS, no barriers, no atomics, direct output write.
// Input dtype detected from A[0][0] (self-loop: fp32 word == 1.0f).

constexpr int GN  = 2048;
constexpr int GHF = 512;

using sh8    = __attribute__((ext_vector_type(8))) short;          // 8 bf16
using us4g   = __attribute__((ext_vector_type(4))) unsigned short;
using f32x4g = __attribute__((ext_vector_type(4))) float;
using u32x4g = __attribute__((ext_vector_type(4))) unsigned int;
using i32x4g = __attribute__((ext_vector_type(4))) int;

__device__ inline float gat_bf2f(unsigned short u) {
    union { unsigned int i; float f; } c; c.i = ((unsigned int)u) << 16; return c.f;
}
__device__ inline unsigned short gat_f2bf(float f) {
    union { float f; unsigned int i; } c; c.f = f;
    return (unsigned short)((c.i + 0x7fffu + ((c.i >> 16) & 1u)) >> 16); // RNE
}
__device__ inline int gat_isf32(const float* __restrict__ Aw) {
    float a = Aw[0];
    return (a == 0.0f) || (a == 1.0f);
}
__device__ inline unsigned int gat_enc(float f) {
    union { float f; unsigned int u; } c; c.f = f;
    return (c.u & 0x80000000u) ? ~c.u : (c.u | 0x80000000u);
}
__device__ inline float gat_dec(unsigned int e) {
    union { float f; unsigned int u; } c;
    c.u = (e & 0x80000000u) ? (e & 0x7fffffffu) : ~e;
    return c.f;
}

__global__ void GraphAttention_62981400429165_kernel() {}

// ---------------- workspace layout (bytes) ----------------
constexpr size_t OFF_HT   = 256;                       // h_t bf16       8 MB
constexpr size_t OFF_ATTS = OFF_HT   + 8388608;        // att_s f32    256 KB
constexpr size_t OFF_E    = OFF_ATTS + 262144;         // exp(n)       256 KB
constexpr size_t OFF_E5   = OFF_E    + 262144;         // exp(.2n)     256 KB
constexpr size_t OFF_MASK = OFF_E5   + 262144;         // bitmask        2 MB
constexpr size_t OFF_MAXN = OFF_MASK + 2097152;        // 32 u32
constexpr size_t OFF_XC   = OFF_MAXN + 256;            // X bf16         4 MB
constexpr size_t OFF_WC   = OFF_XC   + 4194304;        // W bf16       256 KB

// --------------------------------------------------------------------------
// k_mask_conv: blocks 0..65535: A->mask (+block 0 inits maxn).
// 65536..73727: X->bf16. 73728..74239: W->bf16.
// --------------------------------------------------------------------------
__global__ __launch_bounds__(256) void k_mask_conv(const void* __restrict__ Araw,
                                                   const void* __restrict__ Xraw,
                                                   const void* __restrict__ Wraw,
                                                   unsigned long long* __restrict__ mask,
                                                   unsigned int* __restrict__ maxn_enc,
                                                   unsigned short* __restrict__ Xc,
                                                   unsigned short* __restrict__ Wc) {
    int tid = threadIdx.x, blk = blockIdx.x;
    int isf = gat_isf32((const float*)Araw);
    if (blk < 65536) {
        if (blk == 0 && tid < 32) maxn_enc[tid] = 0u;
        size_t idx = (size_t)blk * 256 + tid;
        int nz;
        if (isf) nz = (((const float*)Araw)[idx] != 0.0f);
        else     nz = (((const unsigned short*)Araw)[idx] != 0);
        unsigned long long bal = __ballot(nz);
        if ((tid & 63) == 0) mask[idx >> 6] = bal;
    } else if (blk < 73728) {
        int i = (blk - 65536) * 256 + tid;
        Xc[i] = isf ? gat_f2bf(((const float*)Xraw)[i]) : ((const unsigned short*)Xraw)[i];
    } else {
        int i = (blk - 73728) * 256 + tid;
        Wc[i] = isf ? gat_f2bf(((const float*)Wraw)[i]) : ((const unsigned short*)Wraw)[i];
    }
}

// --------------------------------------------------------------------------
// k_gemm1: h = X @ W per (b,h) + fused att epilogue (att_s, E, E5, maxn).
// grid 256 (bh*8+it) x 256 (4 waves x 64 rows).
// --------------------------------------------------------------------------
constexpr int LDW = 264;
__global__ __launch_bounds__(256) void k_gemm1(const unsigned short* __restrict__ Xc,
                                               const unsigned short* __restrict__ Wc,
                                               const void* __restrict__ aSraw,
                                               const void* __restrict__ aNraw,
                                               const float* __restrict__ Aw,
                                               unsigned short* __restrict__ h_t,
                                               float* __restrict__ att_s,
                                               float* __restrict__ Eb,
                                               float* __restrict__ E5b,
                                               unsigned int* __restrict__ maxn_enc) {
    int blk = blockIdx.x;
    int bh = blk >> 3, it = blk & 7;
    int b = bh >> 3, hh = bh & 7;
    int isf = gat_isf32(Aw);
    __shared__ unsigned short Wt[64 * LDW];
    for (int idx = threadIdx.x; idx < 256 * 64; idx += 256) {
        int k = idx >> 6, col = idx & 63;
        Wt[col * LDW + k] = Wc[(hh * 256 + k) * 64 + col];
    }
    __syncthreads();
#if defined(__gfx950__)
    int wave = threadIdx.x >> 6, lane = threadIdx.x & 63;
    int lrw = lane & 15, quad = lane >> 4;
    int row0 = it * 256 + wave * 64;
    f32x4g acc[4][4] = {};
    for (int k0 = 0; k0 < 256; k0 += 32) {
        sh8 a[4], w[4];
        for (int rt = 0; rt < 4; rt++)
            a[rt] = *(const sh8*)&Xc[((size_t)(b * GN) + row0 + rt * 16 + lrw) * 256 + k0 + quad * 8];
        for (int ct = 0; ct < 4; ct++)
            w[ct] = *(const sh8*)&Wt[(ct * 16 + lrw) * LDW + k0 + quad * 8];
        for (int rt = 0; rt < 4; rt++)
            for (int ct = 0; ct < 4; ct++)
                acc[rt][ct] = __builtin_amdgcn_mfma_f32_16x16x32_bf16(a[rt], w[ct], acc[rt][ct], 0, 0, 0);
    }
    for (int rt = 0; rt < 4; rt++)
        for (int ct = 0; ct < 4; ct++) {
            int col = ct * 16 + lrw;
            int row = row0 + rt * 16 + quad * 4;
            us4g v;
            v[0] = gat_f2bf(acc[rt][ct][0]);
            v[1] = gat_f2bf(acc[rt][ct][1]);
            v[2] = gat_f2bf(acc[rt][ct][2]);
            v[3] = gat_f2bf(acc[rt][ct][3]);
            *(us4g*)&h_t[((size_t)(bh * 64 + col)) * GN + row] = v;
        }
    // ---- fused att epilogue: att_s, E, E5, maxn ----
    float as_l[4], an_l[4];
    for (int ct = 0; ct < 4; ct++) {
        int col = hh * 64 + ct * 16 + lrw;
        as_l[ct] = isf ? ((const float*)aSraw)[col] : gat_bf2f(((const unsigned short*)aSraw)[col]);
        an_l[ct] = isf ? ((const float*)aNraw)[col] : gat_bf2f(((const unsigned short*)aNraw)[col]);
    }
    float wmax = -3e38f;
    for (int rt = 0; rt < 4; rt++)
        for (int r = 0; r < 4; r++) {
            float ps = acc[rt][0][r] * as_l[0] + acc[rt][1][r] * as_l[1]
                     + acc[rt][2][r] * as_l[2] + acc[rt][3][r] * as_l[3];
            float pn = acc[rt][0][r] * an_l[0] + acc[rt][1][r] * an_l[1]
                     + acc[rt][2][r] * an_l[2] + acc[rt][3][r] * an_l[3];
            for (int off = 1; off < 16; off <<= 1) {
                ps += __shfl_xor(ps, off);
                pn += __shfl_xor(pn, off);
            }
            int row = row0 + rt * 16 + quad * 4 + r;
            if (lrw == 0) {
                att_s[bh * GN + row] = ps;
                Eb[bh * GN + row]  = __expf(pn);
                E5b[bh * GN + row] = __expf(0.2f * pn);
            }
            wmax = fmaxf(wmax, pn);
        }
    wmax = fmaxf(wmax, __shfl_xor(wmax, 16));
    wmax = fmaxf(wmax, __shfl_xor(wmax, 32));
    if (lane == 0) atomicMax(&maxn_enc[bh], gat_enc(wmax));
#else
    int row = it * 256 + threadIdx.x;
    float hrow[64];
    for (int col = 0; col < 64; col++) {
        float s = 0.f;
        for (int k = 0; k < 256; k++)
            s += gat_bf2f(Xc[((size_t)(b * GN) + row) * 256 + k]) * gat_bf2f(Wt[col * LDW + k]);
        hrow[col] = s;
        h_t[((size_t)(bh * 64 + col)) * GN + row] = gat_f2bf(s);
    }
    float ps = 0.f, pn = 0.f;
    for (int col = 0; col < 64; col++) {
        float as = isf ? ((const float*)aSraw)[hh * 64 + col] : gat_bf2f(((const unsigned short*)aSraw)[hh * 64 + col]);
        float an = isf ? ((const float*)aNraw)[hh * 64 + col] : gat_bf2f(((const unsigned short*)aNraw)[hh * 64 + col]);
        ps += hrow[col] * as;
        pn += hrow[col] * an;
    }
    att_s[bh * GN + row] = ps;
    Eb[bh * GN + row]  = __expf(pn);
    E5b[bh * GN + row] = __expf(0.2f * pn);
    atomicMax(&maxn_enc[bh], gat_enc(pn));
#endif
}

// --------------------------------------------------------------------------
// k_attn_av: out = relu( softmax(P) @ h ). Table-based P, no transcendentals
// in the loop. grid 2048 (bh = blk&31, it = blk>>5 -> 32 rows), 128 thr =
// 2 waves x 16 rows (one A-frag each) -> 4096 waves (4/SIMD).
// --------------------------------------------------------------------------
__global__ __launch_bounds__(128, 4) void k_attn_av(const unsigned int* __restrict__ mask32,
                                                    const unsigned short* __restrict__ h_t,
                                                    const float* __restrict__ att_s,
                                                    const float* __restrict__ Eb,
                                                    const float* __restrict__ E5b,
                                                    const unsigned int* __restrict__ maxn_enc,
                                                    const float* __restrict__ Aw,
                                                    void* __restrict__ outv) {
    int blk = blockIdx.x;
    int bh = blk & 31, it = blk >> 5;
    int b = bh >> 3, hh = bh & 7;
    int i0 = it * 32;
    int tid = threadIdx.x;
    int isf = gat_isf32(Aw);
    float maxn = gat_dec(maxn_enc[bh]);
    const float* Ep  = Eb  + (size_t)bh * GN;
    const float* E5p = E5b + (size_t)bh * GN;
    const unsigned short* hb = h_t + (size_t)bh * 64 * GN;
#if defined(__gfx950__)
    int wave = tid >> 6, lane = tid & 63, lrw = lane & 15, quad = lane >> 4;
    int kq = quad * 8;
    int row0 = i0 + wave * 16 + lrw;
    float s0 = att_s[bh * GN + row0];
    float z0 = s0 + maxn;
    float c0 = fmaxf(z0, 0.2f * z0);                 // >= true row max
    float k1 = __expf(s0 - c0), k2 = __expf(0.2f * s0 - c0), T0 = __expf(-s0);
    const unsigned int* mr0 = mask32 + ((size_t)(b * GN) + row0) * 64;
    f32x4g acc[4] = {};
    f32x4g accl = {};
    sh8 ones;
#pragma unroll
    for (int e = 0; e < 8; e++) ones[e] = (short)0x3f80;  // bf16 1.0

    for (int jg = 0; jg < 16; jg++) {                // 16 groups x 4 jc
        u32x4g mw4 = *(const u32x4g*)&mr0[jg * 4];
#pragma unroll
        for (int sj = 0; sj < 4; sj++) {
            int jc = jg * 4 + sj;
            int jq = jc * 32 + kq;
            f32x4g eA  = *(const f32x4g*)&Ep[jq];
            f32x4g eB  = *(const f32x4g*)&Ep[jq + 4];
            f32x4g e5A = *(const f32x4g*)&E5p[jq];
            f32x4g e5B = *(const f32x4g*)&E5p[jq + 4];
            unsigned int w0 = mw4[sj] >> kq;
            unsigned int q0[8];
#pragma unroll
            for (int e = 0; e < 8; e++) {
                float Ev  = (e < 4) ? eA[e]  : eB[e - 4];
                float E5v = (e < 4) ? e5A[e] : e5B[e - 4];
                float p = (Ev > T0) ? (k1 * Ev) : (k2 * E5v);
                p = ((w0 >> e) & 1u) ? p : 0.0f;
                q0[e] = __float_as_uint(p);
            }
            i32x4g f0;
#pragma unroll
            for (int pp = 0; pp < 4; pp++)           // trunc pack (bias cancels in l)
                f0[pp] = (int)((q0[2 * pp] >> 16) | (q0[2 * pp + 1] & 0xffff0000u));
            sh8 af = *(sh8*)&f0;
#pragma unroll
            for (int ct = 0; ct < 4; ct++) {
                sh8 bf = *(const sh8*)&hb[((size_t)(ct * 16 + lrw)) * GN + jq];
                acc[ct] = __builtin_amdgcn_mfma_f32_16x16x32_bf16(af, bf, acc[ct], 0, 0, 0);
            }
            accl = __builtin_amdgcn_mfma_f32_16x16x32_bf16(af, ones, accl, 0, 0, 0);
        }
    }
#pragma unroll
    for (int r = 0; r < 4; r++) {
        float li = 1.0f / accl[r];                   // row quad*4+r, same lane
        int ra = i0 + wave * 16 + quad * 4 + r;
#pragma unroll
        for (int ct = 0; ct < 4; ct++) {
            int col = hh * 64 + ct * 16 + lrw;
            float v = acc[ct][r] * li; v = v > 0.f ? v : 0.f;
            size_t o = ((size_t)(b * GN) + ra) * GHF + col;
            if (isf) ((float*)outv)[o] = v;
            else     ((unsigned short*)outv)[o] = gat_f2bf(v);
        }
    }
#else
    // correctness-only fallback: thread -> (row, 16-col quarter)
    int row = i0 + (tid >> 2), chh = (tid & 3) * 16;
    const unsigned int* mr = mask32 + ((size_t)(b * GN) + row) * 64;
    float s = att_s[bh * GN + row];
    float z = s + maxn;
    float c = fmaxf(z, 0.2f * z);
    float k1 = __expf(s - c), k2 = __expf(0.2f * s - c), T0 = __expf(-s);
    float l = 0.f;
    float accS[16] = {};
    for (int j = 0; j < GN; j++) {
        if (!((mr[j >> 5] >> (j & 31)) & 1u)) continue;
        float Ev = Ep[j], E5v = E5p[j];
        float p = (Ev > T0) ? (k1 * Ev) : (k2 * E5v);
        union { float f; unsigned int u; } t; t.f = p; t.u &= 0xffff0000u;
        l += t.f;
        for (int cc = 0; cc < 16; cc++)
            accS[cc] += t.f * gat_bf2f(hb[(size_t)(chh + cc) * GN + j]);
    }
    float li = 1.0f / l;
    for (int cc = 0; cc < 16; cc++) {
        float v = accS[cc] * li; v = v > 0.f ? v : 0.f;
        size_t oi = ((size_t)(b * GN) + row) * GHF + hh * 64 + chh + cc;
        if (isf) ((float*)outv)[oi] = v;
        else     ((unsigned short*)outv)[oi] = gat_f2bf(v);
    }
#endif
}

// --------------------------------------------------------------------------
extern "C" void kernel_launch(void* const* d_in, const int* in_sizes, int n_in,
                              void* d_out, int out_size, void* d_ws, size_t ws_size,
                              hipStream_t stream) {
    const void* X  = d_in[0];
    const void* A  = d_in[1];
    const void* W  = d_in[2];
    const void* aS = d_in[3];
    const void* aN = d_in[4];

    char* ws = (char*)d_ws;
    unsigned short* h_t = (unsigned short*)(ws + OFF_HT);
    float* att_s = (float*)(ws + OFF_ATTS);
    float* Eb    = (float*)(ws + OFF_E);
    float* E5b   = (float*)(ws + OFF_E5);
    unsigned long long* mask = (unsigned long long*)(ws + OFF_MASK);
    unsigned int* maxn_enc = (unsigned int*)(ws + OFF_MAXN);
    unsigned short* Xc = (unsigned short*)(ws + OFF_XC);
    unsigned short* Wc = (unsigned short*)(ws + OFF_WC);

    k_mask_conv<<<74240, 256, 0, stream>>>(A, X, W, mask, maxn_enc, Xc, Wc);
    k_gemm1<<<256, 256, 0, stream>>>(Xc, Wc, aS, aN, (const float*)A,
                                     h_t, att_s, Eb, E5b, maxn_enc);
    k_attn_av<<<2048, 128, 0, stream>>>((const unsigned int*)mask, h_t,
                                        att_s, Eb, E5b, maxn_enc,
                                        (const float*)A, d_out);
}